// Round 25
// baseline (447.750 us; speedup 1.0000x reference)
//
#include <hip/hip_runtime.h>
#include <cmath>

#define B_ 2
#define S_ 512
#define D_ 1024
#define H_ 16
#define HD 64
#define M_ 8192
#define HDIM 1024
#define SCALE 0.125f
#define LCAP 12    // per-lane private candidates; 16 lanes/query -> top-192 screen
#define NRES 3     // rescored candidates per lane (top-48 of 192 by key)

using bf16x8 = __attribute__((ext_vector_type(8))) short;
using f32x4  = __attribute__((ext_vector_type(4))) float;

// pack two f32 (hi,lo) -> one u32 holding [bf16(lo) | bf16(hi)<<16] (truncation)
__device__ inline unsigned pkbf(unsigned hi, unsigned lo) {
    return __builtin_amdgcn_perm(hi, lo, 0x07060302u);
}
// monotone u16 sort keys for 2 packed bf16 (order-preserving for floats)
__device__ inline unsigned key2(unsigned u) {
    unsigned m = u & 0x80008000u;
    return u ^ (m - (m >> 15)) ^ 0x80008000u;
}

// DPP lane moves (full-rate VALU). 0x140=row_mirror (i^15 within 16),
// 0x141=row_half_mirror (i^7), 0x4E=quad_perm xor2, 0xB1=quad_perm xor1.
template<int CTRL>
__device__ inline int dppmov(int x) {
    return __builtin_amdgcn_update_dpp(0, x, CTRL, 0xF, 0xF, true);
}

// ---------------- K0: memk f32 -> bf16 prepass (truncation) ----------------
__global__ __launch_bounds__(256) void tobf16(
    const float* __restrict__ in, unsigned short* __restrict__ out)
{
    size_t i = ((size_t)blockIdx.x*256 + threadIdx.x) * 8;
    f32x4 a = *(const f32x4*)&in[i];
    f32x4 b = *(const f32x4*)&in[i+4];
    union { bf16x8 v; unsigned u[4]; } u;
    u.u[0] = pkbf(__float_as_uint(a.y), __float_as_uint(a.x));
    u.u[1] = pkbf(__float_as_uint(a.w), __float_as_uint(a.z));
    u.u[2] = pkbf(__float_as_uint(b.y), __float_as_uint(b.x));
    u.u[3] = pkbf(__float_as_uint(b.w), __float_as_uint(b.z));
    *(bf16x8*)&out[i] = u.v;
}

// ---------------- K-1: weight transpose + split (f32 -> bf16 hi/lo, [n][k]) -
// grid (32,32,3), 256 thr. z: 0=Wk 1=Wv 2=Wo.  (Wq stays f32 path: top-k
// selection is discontinuous in q; k/v/out are smooth/linear in their GEMMs.)
__global__ __launch_bounds__(256) void wsplitT(
    const float* __restrict__ wk, const float* __restrict__ wv,
    const float* __restrict__ wo,
    unsigned short* __restrict__ kvbase, unsigned short* __restrict__ wobase)
{
    const int z = blockIdx.z;
    const float* src = (z==0)?wk:((z==1)?wv:wo);
    unsigned short* dsthi = (z<2) ? (kvbase + (size_t)z*2097152) : wobase;
    unsigned short* dstlo = dsthi + 1048576;
    const int r0 = blockIdx.y*32, c0 = blockIdx.x*32;
    __shared__ float t[32][33];
    const int tid = threadIdx.x;
    {
        int row = tid >> 3, col4 = (tid & 7) << 2;
        f32x4 v = *(const f32x4*)&src[(size_t)(r0+row)*HDIM + c0 + col4];
        t[row][col4+0]=v.x; t[row][col4+1]=v.y; t[row][col4+2]=v.z; t[row][col4+3]=v.w;
    }
    __syncthreads();
    {
        int n = tid >> 3, k4 = (tid & 7) << 2;   // WT[n][k] = W[k][n]
        float x0 = t[k4+0][n], x1 = t[k4+1][n], x2 = t[k4+2][n], x3 = t[k4+3][n];
        unsigned h0 = pkbf(__float_as_uint(x1), __float_as_uint(x0));
        unsigned h1 = pkbf(__float_as_uint(x3), __float_as_uint(x2));
        float l0f = x0 - __uint_as_float(__float_as_uint(x0) & 0xFFFF0000u);
        float l1f = x1 - __uint_as_float(__float_as_uint(x1) & 0xFFFF0000u);
        float l2f = x2 - __uint_as_float(__float_as_uint(x2) & 0xFFFF0000u);
        float l3f = x3 - __uint_as_float(__float_as_uint(x3) & 0xFFFF0000u);
        unsigned L0 = pkbf(__float_as_uint(l1f), __float_as_uint(l0f));
        unsigned L1 = pkbf(__float_as_uint(l3f), __float_as_uint(l2f));
        size_t off = (size_t)(c0 + n)*HDIM + r0 + k4;
        uint2 hh; hh.x = h0; hh.y = h1;
        uint2 ll; ll.x = L0; ll.y = L1;
        *(uint2*)&dsthi[off] = hh;
        *(uint2*)&dstlo[off] = ll;
    }
}

// ---------------- K1q: Q projection GEMM (f32 vector, 64x64 tile) ----------
// q feeds the top-k screen; selection is discontinuous in q, so q must track
// the reference f32 path bit-closely. Identical to the R0-R23 kernel.
__global__ __launch_bounds__(256) void q_gemm_f32(
    const float* __restrict__ A, const float* __restrict__ W,
    const float* __restrict__ bias, float* __restrict__ out)
{
    const int rb = blockIdx.y*64, cb = blockIdx.x*64;
    __shared__ float As[16][68];
    __shared__ float Bs[16][68];
    const int tid = threadIdx.x;
    const int ty = tid>>4, tx = tid&15;
    const int ar = tid>>2, ac4 = (tid&3)<<2;
    const int bkr = tid>>4, bc4 = (tid&15)<<2;
    float acc[4][4] = {};
    for (int kb=0; kb<D_; kb+=16) {
        float4 av  = *(const float4*)&A[(size_t)(rb+ar)*D_ + kb + ac4];
        float4 bvv = *(const float4*)&W[(size_t)(kb+bkr)*HDIM + cb + bc4];
        __syncthreads();
        As[ac4+0][ar]=av.x; As[ac4+1][ar]=av.y; As[ac4+2][ar]=av.z; As[ac4+3][ar]=av.w;
        *(float4*)&Bs[bkr][bc4] = bvv;
        __syncthreads();
        #pragma unroll
        for (int kk=0; kk<16; kk++) {
            float a[4], b[4];
            *(float4*)a = *(const float4*)&As[kk][ty<<2];
            *(float4*)b = *(const float4*)&Bs[kk][tx<<2];
            #pragma unroll
            for (int i=0;i<4;i++)
                #pragma unroll
                for (int j=0;j<4;j++) acc[i][j] += a[i]*b[j];
        }
    }
    const int c0 = cb + (tx<<2);
    float4 bb = *(const float4*)&bias[c0];
    const int h = c0>>6, dd = c0&63;
    #pragma unroll
    for (int i=0;i<4;i++) {
        int n = rb + (ty<<2) + i;
        int b = n>>9, s = n&511;
        float4 r;
        r.x = acc[i][0]+bb.x; r.y = acc[i][1]+bb.y;
        r.z = acc[i][2]+bb.z; r.w = acc[i][3]+bb.w;
        *(float4*)&out[((size_t)(b*H_+h)*S_ + s)*HD + dd] = r;
    }
}

// ---------------- K1kv: K/V projection GEMM (split-bf16 MFMA, 128x128) -----
// grid (8,8,2), 256 thr (4 waves). C = A*W + bias via AhWh + AhWl + AlWh.
// Error ~1e-5 abs; k enters smooth softmax, v enters linearly -> safe.
__global__ __launch_bounds__(256) void kv_mfma(
    const float* __restrict__ A, const unsigned short* __restrict__ wtbase,
    const float* __restrict__ bk, const float* __restrict__ bv,
    float* __restrict__ ko, float* __restrict__ vo)
{
    const int z = blockIdx.z;
    const unsigned short* WThi = wtbase + (size_t)z*2097152;
    const unsigned short* WTlo = WThi + 1048576;
    const float* bias = z ? bv : bk;
    float* out        = z ? vo : ko;
    const int rb = blockIdx.y*128, cb = blockIdx.x*128;
    __shared__ __align__(16) unsigned short Ah[128][40], Al[128][40];
    __shared__ __align__(16) unsigned short Bh[128][40], Bl[128][40];
    const int tid = threadIdx.x;
    const int lane = tid & 63, w = tid >> 6;
    const int wr = w >> 1, wc = w & 1;
    const int fr = lane & 15, fcq = lane >> 4;
    const int arow = tid >> 1, acol = (tid & 1) << 4;
    f32x4 acc[4][4];
    #pragma unroll
    for (int i = 0; i < 4; i++)
        #pragma unroll
        for (int j = 0; j < 4; j++) acc[i][j] = (f32x4){0.f,0.f,0.f,0.f};

    for (int kb = 0; kb < HDIM; kb += 32) {
        {   // stage A 128x32: load 16 f32, split hi/lo
            const float* ap = &A[(size_t)(rb+arow)*HDIM + kb + acol];
            f32x4 x0 = *(const f32x4*)ap,     x1 = *(const f32x4*)(ap+4);
            f32x4 x2 = *(const f32x4*)(ap+8), x3 = *(const f32x4*)(ap+12);
            union { bf16x8 v; unsigned u[4]; } h0, h1, l0, l1;
            h0.u[0]=pkbf(__float_as_uint(x0.y),__float_as_uint(x0.x));
            h0.u[1]=pkbf(__float_as_uint(x0.w),__float_as_uint(x0.z));
            h0.u[2]=pkbf(__float_as_uint(x1.y),__float_as_uint(x1.x));
            h0.u[3]=pkbf(__float_as_uint(x1.w),__float_as_uint(x1.z));
            h1.u[0]=pkbf(__float_as_uint(x2.y),__float_as_uint(x2.x));
            h1.u[1]=pkbf(__float_as_uint(x2.w),__float_as_uint(x2.z));
            h1.u[2]=pkbf(__float_as_uint(x3.y),__float_as_uint(x3.x));
            h1.u[3]=pkbf(__float_as_uint(x3.w),__float_as_uint(x3.z));
            f32x4 e0, e1, e2, e3;
            #define LOF(dst, src) \
                dst.x = src.x - __uint_as_float(__float_as_uint(src.x)&0xFFFF0000u); \
                dst.y = src.y - __uint_as_float(__float_as_uint(src.y)&0xFFFF0000u); \
                dst.z = src.z - __uint_as_float(__float_as_uint(src.z)&0xFFFF0000u); \
                dst.w = src.w - __uint_as_float(__float_as_uint(src.w)&0xFFFF0000u);
            LOF(e0,x0) LOF(e1,x1) LOF(e2,x2) LOF(e3,x3)
            #undef LOF
            l0.u[0]=pkbf(__float_as_uint(e0.y),__float_as_uint(e0.x));
            l0.u[1]=pkbf(__float_as_uint(e0.w),__float_as_uint(e0.z));
            l0.u[2]=pkbf(__float_as_uint(e1.y),__float_as_uint(e1.x));
            l0.u[3]=pkbf(__float_as_uint(e1.w),__float_as_uint(e1.z));
            l1.u[0]=pkbf(__float_as_uint(e2.y),__float_as_uint(e2.x));
            l1.u[1]=pkbf(__float_as_uint(e2.w),__float_as_uint(e2.z));
            l1.u[2]=pkbf(__float_as_uint(e3.y),__float_as_uint(e3.x));
            l1.u[3]=pkbf(__float_as_uint(e3.w),__float_as_uint(e3.z));
            *(bf16x8*)&Ah[arow][acol]   = h0.v;
            *(bf16x8*)&Ah[arow][acol+8] = h1.v;
            *(bf16x8*)&Al[arow][acol]   = l0.v;
            *(bf16x8*)&Al[arow][acol+8] = l1.v;
        }
        {   // stage WT 128(n)x32(k) bf16 (pre-split): plain copies
            size_t off = (size_t)(cb+arow)*HDIM + kb + acol;
            *(uint4*)&Bh[arow][acol]   = *(const uint4*)&WThi[off];
            *(uint4*)&Bh[arow][acol+8] = *(const uint4*)&WThi[off+8];
            *(uint4*)&Bl[arow][acol]   = *(const uint4*)&WTlo[off];
            *(uint4*)&Bl[arow][acol+8] = *(const uint4*)&WTlo[off+8];
        }
        __syncthreads();
        bf16x8 ah[4], al[4], bh[4], bl[4];
        #pragma unroll
        for (int fi = 0; fi < 4; fi++) {
            ah[fi] = *(const bf16x8*)&Ah[wr*64 + fi*16 + fr][8*fcq];
            al[fi] = *(const bf16x8*)&Al[wr*64 + fi*16 + fr][8*fcq];
        }
        #pragma unroll
        for (int fj = 0; fj < 4; fj++) {
            bh[fj] = *(const bf16x8*)&Bh[wc*64 + fj*16 + fr][8*fcq];
            bl[fj] = *(const bf16x8*)&Bl[wc*64 + fj*16 + fr][8*fcq];
        }
        #pragma unroll
        for (int fi = 0; fi < 4; fi++)
            #pragma unroll
            for (int fj = 0; fj < 4; fj++) {
                acc[fi][fj] = __builtin_amdgcn_mfma_f32_16x16x32_bf16(ah[fi], bh[fj], acc[fi][fj], 0,0,0);
                acc[fi][fj] = __builtin_amdgcn_mfma_f32_16x16x32_bf16(ah[fi], bl[fj], acc[fi][fj], 0,0,0);
                acc[fi][fj] = __builtin_amdgcn_mfma_f32_16x16x32_bf16(al[fi], bh[fj], acc[fi][fj], 0,0,0);
            }
        __syncthreads();
    }
    // epilogue: bias + scatter to (b,h,s,d) layout
    #pragma unroll
    for (int fi = 0; fi < 4; fi++)
        #pragma unroll
        for (int fj = 0; fj < 4; fj++) {
            int c0 = cb + wc*64 + fj*16 + fr;
            float bv2 = bias[c0];
            int h = c0 >> 6, dd = c0 & 63;
            #pragma unroll
            for (int r = 0; r < 4; r++) {
                int n = rb + wr*64 + fi*16 + 4*fcq + r;
                int bi = n >> 9, s = n & 511;
                out[((size_t)(bi*H_ + h)*S_ + s)*HD + dd] = acc[fi][fj][r] + bv2;
            }
        }
}

// ---------------- K6: output projection GEMM (split-bf16 MFMA) -------------
__global__ __launch_bounds__(256) void out_mfma(
    const float* __restrict__ A, const unsigned short* __restrict__ WThi_,
    float* __restrict__ out)
{
    const unsigned short* WThi = WThi_;
    const unsigned short* WTlo = WThi + 1048576;
    const int rb = blockIdx.y*128, cb = blockIdx.x*128;
    __shared__ __align__(16) unsigned short Ah[128][40], Al[128][40];
    __shared__ __align__(16) unsigned short Bh[128][40], Bl[128][40];
    const int tid = threadIdx.x;
    const int lane = tid & 63, w = tid >> 6;
    const int wr = w >> 1, wc = w & 1;
    const int fr = lane & 15, fcq = lane >> 4;
    const int arow = tid >> 1, acol = (tid & 1) << 4;
    f32x4 acc[4][4];
    #pragma unroll
    for (int i = 0; i < 4; i++)
        #pragma unroll
        for (int j = 0; j < 4; j++) acc[i][j] = (f32x4){0.f,0.f,0.f,0.f};

    for (int kb = 0; kb < HDIM; kb += 32) {
        {
            const float* ap = &A[(size_t)(rb+arow)*HDIM + kb + acol];
            f32x4 x0 = *(const f32x4*)ap,     x1 = *(const f32x4*)(ap+4);
            f32x4 x2 = *(const f32x4*)(ap+8), x3 = *(const f32x4*)(ap+12);
            union { bf16x8 v; unsigned u[4]; } h0, h1, l0, l1;
            h0.u[0]=pkbf(__float_as_uint(x0.y),__float_as_uint(x0.x));
            h0.u[1]=pkbf(__float_as_uint(x0.w),__float_as_uint(x0.z));
            h0.u[2]=pkbf(__float_as_uint(x1.y),__float_as_uint(x1.x));
            h0.u[3]=pkbf(__float_as_uint(x1.w),__float_as_uint(x1.z));
            h1.u[0]=pkbf(__float_as_uint(x2.y),__float_as_uint(x2.x));
            h1.u[1]=pkbf(__float_as_uint(x2.w),__float_as_uint(x2.z));
            h1.u[2]=pkbf(__float_as_uint(x3.y),__float_as_uint(x3.x));
            h1.u[3]=pkbf(__float_as_uint(x3.w),__float_as_uint(x3.z));
            f32x4 e0, e1, e2, e3;
            #define LOF(dst, src) \
                dst.x = src.x - __uint_as_float(__float_as_uint(src.x)&0xFFFF0000u); \
                dst.y = src.y - __uint_as_float(__float_as_uint(src.y)&0xFFFF0000u); \
                dst.z = src.z - __uint_as_float(__float_as_uint(src.z)&0xFFFF0000u); \
                dst.w = src.w - __uint_as_float(__float_as_uint(src.w)&0xFFFF0000u);
            LOF(e0,x0) LOF(e1,x1) LOF(e2,x2) LOF(e3,x3)
            #undef LOF
            l0.u[0]=pkbf(__float_as_uint(e0.y),__float_as_uint(e0.x));
            l0.u[1]=pkbf(__float_as_uint(e0.w),__float_as_uint(e0.z));
            l0.u[2]=pkbf(__float_as_uint(e1.y),__float_as_uint(e1.x));
            l0.u[3]=pkbf(__float_as_uint(e1.w),__float_as_uint(e1.z));
            l1.u[0]=pkbf(__float_as_uint(e2.y),__float_as_uint(e2.x));
            l1.u[1]=pkbf(__float_as_uint(e2.w),__float_as_uint(e2.z));
            l1.u[2]=pkbf(__float_as_uint(e3.y),__float_as_uint(e3.x));
            l1.u[3]=pkbf(__float_as_uint(e3.w),__float_as_uint(e3.z));
            *(bf16x8*)&Ah[arow][acol]   = h0.v;
            *(bf16x8*)&Ah[arow][acol+8] = h1.v;
            *(bf16x8*)&Al[arow][acol]   = l0.v;
            *(bf16x8*)&Al[arow][acol+8] = l1.v;
        }
        {
            size_t off = (size_t)(cb+arow)*HDIM + kb + acol;
            *(uint4*)&Bh[arow][acol]   = *(const uint4*)&WThi[off];
            *(uint4*)&Bh[arow][acol+8] = *(const uint4*)&WThi[off+8];
            *(uint4*)&Bl[arow][acol]   = *(const uint4*)&WTlo[off];
            *(uint4*)&Bl[arow][acol+8] = *(const uint4*)&WTlo[off+8];
        }
        __syncthreads();
        bf16x8 ah[4], al[4], bh[4], bl[4];
        #pragma unroll
        for (int fi = 0; fi < 4; fi++) {
            ah[fi] = *(const bf16x8*)&Ah[wr*64 + fi*16 + fr][8*fcq];
            al[fi] = *(const bf16x8*)&Al[wr*64 + fi*16 + fr][8*fcq];
        }
        #pragma unroll
        for (int fj = 0; fj < 4; fj++) {
            bh[fj] = *(const bf16x8*)&Bh[wc*64 + fj*16 + fr][8*fcq];
            bl[fj] = *(const bf16x8*)&Bl[wc*64 + fj*16 + fr][8*fcq];
        }
        #pragma unroll
        for (int fi = 0; fi < 4; fi++)
            #pragma unroll
            for (int fj = 0; fj < 4; fj++) {
                acc[fi][fj] = __builtin_amdgcn_mfma_f32_16x16x32_bf16(ah[fi], bh[fj], acc[fi][fj], 0,0,0);
                acc[fi][fj] = __builtin_amdgcn_mfma_f32_16x16x32_bf16(ah[fi], bl[fj], acc[fi][fj], 0,0,0);
                acc[fi][fj] = __builtin_amdgcn_mfma_f32_16x16x32_bf16(al[fi], bh[fj], acc[fi][fj], 0,0,0);
            }
        __syncthreads();
    }
    #pragma unroll
    for (int fi = 0; fi < 4; fi++)
        #pragma unroll
        for (int fj = 0; fj < 4; fj++) {
            int c0 = cb + wc*64 + fj*16 + fr;
            #pragma unroll
            for (int r = 0; r < 4; r++) {
                int n = rb + wr*64 + fi*16 + 4*fcq + r;
                out[(size_t)n*HDIM + c0] = acc[fi][fj][r];
            }
        }
}

// ---------------- K2: RoPE in-place on q,k ----------------
__global__ __launch_bounds__(256) void rope_kernel(
    float* __restrict__ q, float* __restrict__ k,
    const float* __restrict__ cosb, const float* __restrict__ sinb)
{
    int t = blockIdx.x*256 + threadIdx.x;
    int pair = t & 31;
    int s    = (t>>5) & 511;
    int bh   = (t>>14) & 31;
    float* x = (t>>19) ? k : q;
    float* xb = x + ((size_t)(bh*S_ + s))*HD;
    float c  = cosb[s*HD + pair];
    float sn = sinb[s*HD + pair];
    float x1 = xb[pair], x2 = xb[pair+32];
    xb[pair]    = x1*c - x2*sn;
    xb[pair+32] = x2*c + x1*sn;
}

// ---------------- K3: MFMA sim + screen (dbuf, wave-skip ladder) -----------
__global__ __launch_bounds__(1024, 4) void sim_topk_mfma(
    const float* __restrict__ q, const float* __restrict__ memk,
    const unsigned short* __restrict__ kb16,
    float* __restrict__ topV, int* __restrict__ topI)
{
    __shared__ unsigned short sc[2][64][136];
    __shared__ __align__(16) float qs[64][64];
    __shared__ __align__(16) unsigned short Ks[2][128][76];
    const int tid = threadIdx.x;
    int id = blockIdx.x;                 // 0..255
    int virt = (id & 7)*32 + (id >> 3);
    const int bh = virt >> 3, qt = virt & 7;
    const float* qbase = q + ((size_t)bh*S_ + qt*64)*HD;
    const float* kbase = memk + (size_t)bh*M_*HD;
    const unsigned short* k16 = kb16 + (size_t)bh*M_*HD;

    {   // stage q f32 (64x64): one f32x4 per thread
        int r = tid >> 4, c = (tid & 15) << 2;
        *(f32x4*)&qs[r][c] = *(const f32x4*)&qbase[(size_t)r*HD + c];
    }
    __syncthreads();

    const int lane = tid & 63;
    const int w  = tid >> 6;                  // wave 0..15
    const int s8 = w & 7;                     // m-subtile (rows s8*16..+15)
    const int qg = w >> 3;                    // qh-group: qh = 2*qg, 2*qg+1
    const int fr = lane & 15, fc = lane >> 4; // frag row / k-chunk

    bf16x8 bq[2][2];
    #pragma unroll
    for (int j = 0; j < 2; j++)
        #pragma unroll
        for (int kc = 0; kc < 2; kc++) {
            const float* p = &qs[(2*qg + j)*16 + fr][kc*32 + 8*fc];
            union { bf16x8 v; unsigned u[4]; } u;
            #pragma unroll
            for (int jj = 0; jj < 4; jj++)
                u.u[jj] = pkbf(__float_as_uint(p[2*jj+1]), __float_as_uint(p[2*jj]));
            bq[j][kc] = u.v;
        }

    const int ql = tid >> 4, lg = tid & 15;   // query row / lane-in-group
    unsigned xs[LCAP];
    #pragma unroll
    for (int s = 0; s < LCAP; s++) xs[s] = 0u;

    const int srow = tid >> 3, scol = (tid & 7) << 3;

    uint4 pfu;
    {
        uint4 t0 = *(const uint4*)&k16[(size_t)srow*HD + scol];
        *(uint4*)&Ks[0][srow][scol] = t0;
        pfu = *(const uint4*)&k16[(size_t)(128 + srow)*HD + scol];
    }
    __syncthreads();   // Ks[0] ready

    for (int it = 0; it < 64; it++) {
        const int cur = it & 1, nxt = cur ^ 1;
        if (it < 63) {
            *(uint4*)&Ks[nxt][srow][scol] = pfu;
        }
        if (it < 62) {
            pfu = *(const uint4*)&k16[(size_t)((it+2)*128 + srow)*HD + scol];
        }
        {
            bf16x8 a0 = *(const bf16x8*)&Ks[cur][s8*16 + fr][8*fc];
            bf16x8 a1 = *(const bf16x8*)&Ks[cur][s8*16 + fr][32 + 8*fc];
            #pragma unroll
            for (int j = 0; j < 2; j++) {
                f32x4 acc = (f32x4){0.f, 0.f, 0.f, 0.f};
                acc = __builtin_amdgcn_mfma_f32_16x16x32_bf16(a0, bq[j][0], acc, 0,0,0);
                acc = __builtin_amdgcn_mfma_f32_16x16x32_bf16(a1, bq[j][1], acc, 0,0,0);
                unsigned k0 = key2(pkbf(__float_as_uint(acc.y), __float_as_uint(acc.x)));
                unsigned k1 = key2(pkbf(__float_as_uint(acc.w), __float_as_uint(acc.z)));
                uint2 kk; kk.x = k0; kk.y = k1;
                *(uint2*)&sc[cur][(2*qg + j)*16 + fr][s8*16 + 4*fc] = kk;
            }
        }
        if (it > 0) {
            uint4 w0v = *(const uint4*)&sc[cur^1][ql][lg << 3];
            unsigned wbuf[4] = {w0v.x, w0v.y, w0v.z, w0v.w};
            const unsigned ibase = (unsigned)((it-1)*128 + (lg << 3));
            #pragma unroll
            for (int p = 0; p < 4; p++) {
                unsigned wk = wbuf[p];
                unsigned ve = (wk << 16) | (ibase + 2*p);
                unsigned vo = (wk & 0xFFFF0000u) | (ibase + 2*p + 1);
                if (__any(ve > xs[LCAP-1] || vo > xs[LCAP-1])) {
                    #pragma unroll
                    for (int s = 0; s < LCAP; s++) {
                        unsigned mx = xs[s] > ve ? xs[s] : ve;
                        unsigned mn = xs[s] > ve ? ve : xs[s];
                        xs[s] = mx; ve = mn;
                    }
                    #pragma unroll
                    for (int s = 0; s < LCAP; s++) {
                        unsigned mx = xs[s] > vo ? xs[s] : vo;
                        unsigned mn = xs[s] > vo ? vo : xs[s];
                        xs[s] = mx; vo = mn;
                    }
                }
            }
        }
        __syncthreads();
    }
    {
        uint4 w0v = *(const uint4*)&sc[1][ql][lg << 3];
        unsigned wbuf[4] = {w0v.x, w0v.y, w0v.z, w0v.w};
        const unsigned ibase = (unsigned)(63*128 + (lg << 3));
        #pragma unroll
        for (int p = 0; p < 4; p++) {
            unsigned wk = wbuf[p];
            unsigned ve = (wk << 16) | (ibase + 2*p);
            unsigned vo = (wk & 0xFFFF0000u) | (ibase + 2*p + 1);
            if (__any(ve > xs[LCAP-1] || vo > xs[LCAP-1])) {
                #pragma unroll
                for (int s = 0; s < LCAP; s++) {
                    unsigned mx = xs[s] > ve ? xs[s] : ve;
                    unsigned mn = xs[s] > ve ? ve : xs[s];
                    xs[s] = mx; ve = mn;
                }
                #pragma unroll
                for (int s = 0; s < LCAP; s++) {
                    unsigned mx = xs[s] > vo ? xs[s] : vo;
                    unsigned mn = xs[s] > vo ? vo : xs[s];
                    xs[s] = mx; vo = mn;
                }
            }
        }
    }

    unsigned rc[NRES];
    #pragma unroll
    for (int it = 0; it < 48; it++) {
        unsigned gm = xs[0]; int go = lg;
        { unsigned ov=(unsigned)dppmov<0x140>((int)gm); int oo=dppmov<0x140>(go);
          if (ov > gm) { gm = ov; go = oo; } }
        { unsigned ov=(unsigned)dppmov<0x141>((int)gm); int oo=dppmov<0x141>(go);
          if (ov > gm) { gm = ov; go = oo; } }
        { unsigned ov=(unsigned)dppmov<0x4E>((int)gm);  int oo=dppmov<0x4E>(go);
          if (ov > gm) { gm = ov; go = oo; } }
        { unsigned ov=(unsigned)dppmov<0xB1>((int)gm);  int oo=dppmov<0xB1>(go);
          if (ov > gm) { gm = ov; go = oo; } }
        if (go == lg) {
            #pragma unroll
            for (int s = 0; s < LCAP-1; s++) xs[s] = xs[s+1];
            xs[LCAP-1] = 0u;
        }
        if ((it & 15) == lg) rc[it >> 4] = gm;
    }

    float rsv[NRES]; int rsi[NRES];
    #pragma unroll
    for (int s2 = 0; s2 < NRES; s2++) {
        int idx = (int)(rc[s2] & 0xFFFFu);
        const float* kr = &kbase[(size_t)idx * HD];
        float accr = 0.f;
        #pragma unroll
        for (int j = 0; j < 64; j += 4) {
            f32x4 kv = *(const f32x4*)&kr[j];
            f32x4 qv = *(const f32x4*)&qs[ql][j];
            accr += qv.x*kv.x + qv.y*kv.y + qv.z*kv.z + qv.w*kv.w;
        }
        rsv[s2] = accr; rsi[s2] = idx;
    }
    const int qgb = bh*S_ + qt*64;
    float* tVo = &topV[(size_t)(qgb + ql)*32];
    int*   tIo = &topI[(size_t)(qgb + ql)*32];
    #pragma unroll 1
    for (int it = 0; it < 32; it++) {
        float mv = rsv[0]; int ms = 0;
        if (rsv[1] > mv) { mv = rsv[1]; ms = 1; }
        if (rsv[2] > mv) { mv = rsv[2]; ms = 2; }
        int owner = (lg << 2) | ms;
        { float ovf=__int_as_float(dppmov<0x140>(__float_as_int(mv))); int oo=dppmov<0x140>(owner);
          if (ovf>mv || (ovf==mv && oo<owner)) { mv=ovf; owner=oo; } }
        { float ovf=__int_as_float(dppmov<0x141>(__float_as_int(mv))); int oo=dppmov<0x141>(owner);
          if (ovf>mv || (ovf==mv && oo<owner)) { mv=ovf; owner=oo; } }
        { float ovf=__int_as_float(dppmov<0x4E>(__float_as_int(mv)));  int oo=dppmov<0x4E>(owner);
          if (ovf>mv || (ovf==mv && oo<owner)) { mv=ovf; owner=oo; } }
        { float ovf=__int_as_float(dppmov<0xB1>(__float_as_int(mv)));  int oo=dppmov<0xB1>(owner);
          if (ovf>mv || (ovf==mv && oo<owner)) { mv=ovf; owner=oo; } }
        if ((owner >> 2) == lg) {
            int ms2 = owner & 3;
            int idx = rsi[0];
            if (ms2 == 1) idx = rsi[1];
            else if (ms2 == 2) idx = rsi[2];
            if (ms2 == 0) rsv[0] = -INFINITY;
            else if (ms2 == 1) rsv[1] = -INFINITY;
            else rsv[2] = -INFINITY;
            tVo[it] = mv; tIo[it] = idx;
        }
    }
}

// ---------------- K5: fused local-causal + memory attention ----------------
__global__ __launch_bounds__(256) void attn_fused(
    const float* __restrict__ q, const float* __restrict__ k, const float* __restrict__ v,
    const float* __restrict__ topV, const int* __restrict__ topI,
    const float* __restrict__ memv, float* __restrict__ attn)
{
    __shared__ float Ks[64][68];
    __shared__ float Vs[64][68];
    __shared__ float Qs[32][68];
    __shared__ float pt[32][68];
    const int tid = threadIdx.x;
    const int qt = blockIdx.x, bh = blockIdx.y;
    const float* qbase = q + ((size_t)bh*S_ + qt*32)*HD;
    {
        int fi = tid; int r = fi>>4, c = (fi&15)<<2;
        float4 t4 = *(const float4*)&qbase[(size_t)r*HD + c];
        t4.x*=SCALE; t4.y*=SCALE; t4.z*=SCALE; t4.w*=SCALE;
        *(float4*)&Qs[r][c] = t4;
        fi = tid+256; r = fi>>4; c = (fi&15)<<2;
        t4 = *(const float4*)&qbase[(size_t)r*HD + c];
        t4.x*=SCALE; t4.y*=SCALE; t4.z*=SCALE; t4.w*=SCALE;
        *(float4*)&Qs[r][c] = t4;
    }
    __syncthreads();
    const int ql = tid>>3, lg = tid&7;
    const int dd0 = lg<<3;
    float qreg[64];
    #pragma unroll
    for (int j=0;j<64;j+=4) *(float4*)&qreg[j] = *(const float4*)&Qs[ql][j];
    const int qpos = qt*32 + ql;
    const size_t qg = (size_t)bh*S_ + qpos;

    float m = -INFINITY, l = 0.f;
    float acc[8] = {0,0,0,0,0,0,0,0};
    const float* tvp = &topV[qg*32];
    const int*   tip = &topI[qg*32];
    #pragma unroll 8
    for (int j=0;j<32;j++) m = fmaxf(m, tvp[j]*SCALE);
    #pragma unroll 4
    for (int j=0;j<32;j++) {
        float p = __expf(tvp[j]*SCALE - m);
        l += p;
        const float* mvr = &memv[((size_t)bh*M_ + tip[j])*HD + dd0];
        float4 a  = *(const float4*)&mvr[0];
        float4 b2 = *(const float4*)&mvr[4];
        acc[0]+=p*a.x;  acc[1]+=p*a.y;  acc[2]+=p*a.z;  acc[3]+=p*a.w;
        acc[4]+=p*b2.x; acc[5]+=p*b2.y; acc[6]+=p*b2.z; acc[7]+=p*b2.w;
    }
    const int ntiles = (qt*32 + 31)/64 + 1;
    const float* kb2 = k + ((size_t)bh*S_)*HD;
    const float* vb2 = v + ((size_t)bh*S_)*HD;
    for (int kt=0; kt<ntiles; kt++) {
        __syncthreads();
        for (int fi=tid; fi<1024; fi+=256) {
            int r = fi>>4, c = (fi&15)<<2;
            *(float4*)&Ks[r][c] = *(const float4*)&kb2[(size_t)(kt*64+r)*HD + c];
            *(float4*)&Vs[r][c] = *(const float4*)&vb2[(size_t)(kt*64+r)*HD + c];
        }
        __syncthreads();
        float s8[8];
        #pragma unroll
        for (int rr=0; rr<8; rr++) {
            int row = lg + (rr<<3);
            float acc2 = 0.f;
            #pragma unroll
            for (int j=0;j<64;j+=4) {
                float4 kv = *(const float4*)&Ks[row][j];
                acc2 += qreg[j]*kv.x + qreg[j+1]*kv.y + qreg[j+2]*kv.z + qreg[j+3]*kv.w;
            }
            int kpos = kt*64 + row;
            s8[rr] = (kpos <= qpos) ? acc2 : -INFINITY;
        }
        float tmax = s8[0];
        #pragma unroll
        for (int rr=1; rr<8; rr++) tmax = fmaxf(tmax, s8[rr]);
        #pragma unroll
        for (int off=1; off<8; off<<=1) tmax = fmaxf(tmax, __shfl_xor(tmax, off));
        float mnew = fmaxf(m, tmax);
        float f = __expf(m - mnew);
        l *= f;
        #pragma unroll
        for (int i=0;i<8;i++) acc[i] *= f;
        float psum = 0.f;
        #pragma unroll
        for (int rr=0; rr<8; rr++) {
            float p = __expf(s8[rr] - mnew);
            psum += p;
            pt[ql][lg + (rr<<3)] = p;
        }
        #pragma unroll
        for (int off=1; off<8; off<<=1) psum += __shfl_xor(psum, off);
        l += psum; m = mnew;
        #pragma unroll 8
        for (int r=0; r<64; r++) {
            float p = pt[ql][r];
            float4 a  = *(const float4*)&Vs[r][dd0];
            float4 b2 = *(const float4*)&Vs[r][dd0+4];
            acc[0]+=p*a.x;  acc[1]+=p*a.y;  acc[2]+=p*a.z;  acc[3]+=p*a.w;
            acc[4]+=p*b2.x; acc[5]+=p*b2.y; acc[6]+=p*b2.z; acc[7]+=p*b2.w;
        }
    }
    float inv = 1.0f / l;
    const int b = bh>>4, h = bh&15;
    float4 o;
    o.x=acc[0]*inv; o.y=acc[1]*inv; o.z=acc[2]*inv; o.w=acc[3]*inv;
    *(float4*)&attn[((size_t)(b*S_)+qpos)*HDIM + h*HD + dd0] = o;
    o.x=acc[4]*inv; o.y=acc[5]*inv; o.z=acc[6]*inv; o.w=acc[7]*inv;
    *(float4*)&attn[((size_t)(b*S_)+qpos)*HDIM + h*HD + dd0 + 4] = o;
}

extern "C" void kernel_launch(void* const* d_in, const int* in_sizes, int n_in,
                              void* d_out, int out_size, void* d_ws, size_t ws_size,
                              hipStream_t stream)
{
    const float* hs   = (const float*)d_in[0];
    const float* cosb = (const float*)d_in[1];
    const float* sinb = (const float*)d_in[2];
    const float* memk = (const float*)d_in[3];
    const float* memv = (const float*)d_in[4];
    const float* Wq = (const float*)d_in[5];
    const float* bq = (const float*)d_in[6];
    const float* Wk = (const float*)d_in[7];
    const float* bk = (const float*)d_in[8];
    const float* Wv = (const float*)d_in[9];
    const float* bv = (const float*)d_in[10];
    const float* Wo = (const float*)d_in[11];
    float* out = (float*)d_out;
    float* ws = (float*)d_ws;
    float* qw = ws;                    // 1M floats
    float* kw = ws + 1048576;          // 1M
    float* vw = ws + 2097152;          // 1M
    float* tV = ws + 3145728;          // 512K
    int*   tI = (int*)(ws + 3670016);  // 512K
    // kb16: ws+4194304 .. +12582912 (8.39M float-slots)
    unsigned short* kb16 = (unsigned short*)(ws + 4194304);
    float* ao = ws + 4194304;          // aliases kb16 (dead before attn writes)
    // Wk/Wv^T hi+lo alias kb16 region (dead before tobf16 overwrites):
    unsigned short* wkvT = (unsigned short*)(ws + 4194304);   // 2 z-blocks x 2097152 us
    // Wo^T hi+lo: separate region after kb16:
    unsigned short* woT = (unsigned short*)(ws + 12582912);   // 2097152 us

    wsplitT<<<dim3(32,32,3),256,0,stream>>>(Wk, Wv, Wo, wkvT, woT);
    q_gemm_f32<<<dim3(16,16),256,0,stream>>>(hs, Wq, bq, qw);
    kv_mfma<<<dim3(8,8,2),256,0,stream>>>(hs, wkvT, bk, bv, kw, vw);
    rope_kernel<<<4096,256,0,stream>>>(qw, kw, cosb, sinb);
    tobf16<<<8192,256,0,stream>>>(memk, kb16);   // overwrites wkvT (dead)
    sim_topk_mfma<<<256,1024,0,stream>>>(qw, memk, kb16, tV, tI);
    attn_fused<<<dim3(16,32),256,0,stream>>>(qw, kw, vw, tV, tI, memv, ao);
    out_mfma<<<dim3(8,8),256,0,stream>>>(ao, woT, out);
}

// Round 26
// 421.253 us; speedup vs baseline: 1.0629x; 1.0629x over previous
//
#include <hip/hip_runtime.h>
#include <cmath>

#define B_ 2
#define S_ 512
#define D_ 1024
#define H_ 16
#define HD 64
#define M_ 8192
#define HDIM 1024
#define SCALE 0.125f
#define LCAP 12    // per-lane private candidates; 16 lanes/query -> top-192 screen
#define NRES 3     // rescored candidates per lane (top-48 of 192 by key)

using bf16x8 = __attribute__((ext_vector_type(8))) short;
using f32x4  = __attribute__((ext_vector_type(4))) float;

// pack two f32 (hi,lo) -> one u32 holding [bf16(lo) | bf16(hi)<<16] (truncation)
__device__ inline unsigned pkbf(unsigned hi, unsigned lo) {
    return __builtin_amdgcn_perm(hi, lo, 0x07060302u);
}
// monotone u16 sort keys for 2 packed bf16 (order-preserving for floats)
__device__ inline unsigned key2(unsigned u) {
    unsigned m = u & 0x80008000u;
    return u ^ (m - (m >> 15)) ^ 0x80008000u;
}

// DPP lane moves (full-rate VALU). 0x140=row_mirror (i^15 within 16),
// 0x141=row_half_mirror (i^7), 0x4E=quad_perm xor2, 0xB1=quad_perm xor1.
template<int CTRL>
__device__ inline int dppmov(int x) {
    return __builtin_amdgcn_update_dpp(0, x, CTRL, 0xF, 0xF, true);
}

// ---------------- K0: memk f32 -> bf16 prepass (truncation) ----------------
__global__ __launch_bounds__(256) void tobf16(
    const float* __restrict__ in, unsigned short* __restrict__ out)
{
    size_t i = ((size_t)blockIdx.x*256 + threadIdx.x) * 8;
    f32x4 a = *(const f32x4*)&in[i];
    f32x4 b = *(const f32x4*)&in[i+4];
    union { bf16x8 v; unsigned u[4]; } u;
    u.u[0] = pkbf(__float_as_uint(a.y), __float_as_uint(a.x));
    u.u[1] = pkbf(__float_as_uint(a.w), __float_as_uint(a.z));
    u.u[2] = pkbf(__float_as_uint(b.y), __float_as_uint(b.x));
    u.u[3] = pkbf(__float_as_uint(b.w), __float_as_uint(b.z));
    *(bf16x8*)&out[i] = u.v;
}

// ---------------- K1: QKV projection GEMM (64x64 tile, f32) ----------------
__global__ __launch_bounds__(256) void qkv_gemm(
    const float* __restrict__ A,
    const float* __restrict__ Wq, const float* __restrict__ bq,
    const float* __restrict__ Wk, const float* __restrict__ bk,
    const float* __restrict__ Wv, const float* __restrict__ bv,
    float* __restrict__ qo, float* __restrict__ ko, float* __restrict__ vo)
{
    const int which = blockIdx.z;
    const float* W    = (which==0)?Wq:((which==1)?Wk:Wv);
    const float* bias = (which==0)?bq:((which==1)?bk:bv);
    float* out        = (which==0)?qo:((which==1)?ko:vo);
    const int rb = blockIdx.y*64, cb = blockIdx.x*64;
    __shared__ float As[16][68];
    __shared__ float Bs[16][68];
    const int tid = threadIdx.x;
    const int ty = tid>>4, tx = tid&15;
    const int ar = tid>>2, ac4 = (tid&3)<<2;
    const int bkr = tid>>4, bc4 = (tid&15)<<2;
    float acc[4][4] = {};
    for (int kb=0; kb<D_; kb+=16) {
        float4 av  = *(const float4*)&A[(size_t)(rb+ar)*D_ + kb + ac4];
        float4 bvv = *(const float4*)&W[(size_t)(kb+bkr)*HDIM + cb + bc4];
        __syncthreads();
        As[ac4+0][ar]=av.x; As[ac4+1][ar]=av.y; As[ac4+2][ar]=av.z; As[ac4+3][ar]=av.w;
        *(float4*)&Bs[bkr][bc4] = bvv;
        __syncthreads();
        #pragma unroll
        for (int kk=0; kk<16; kk++) {
            float a[4], b[4];
            *(float4*)a = *(const float4*)&As[kk][ty<<2];
            *(float4*)b = *(const float4*)&Bs[kk][tx<<2];
            #pragma unroll
            for (int i=0;i<4;i++)
                #pragma unroll
                for (int j=0;j<4;j++) acc[i][j] += a[i]*b[j];
        }
    }
    const int c0 = cb + (tx<<2);
    float4 bb = *(const float4*)&bias[c0];
    const int h = c0>>6, dd = c0&63;
    #pragma unroll
    for (int i=0;i<4;i++) {
        int n = rb + (ty<<2) + i;
        int b = n>>9, s = n&511;
        float4 r;
        r.x = acc[i][0]+bb.x; r.y = acc[i][1]+bb.y;
        r.z = acc[i][2]+bb.z; r.w = acc[i][3]+bb.w;
        *(float4*)&out[((size_t)(b*H_+h)*S_ + s)*HD + dd] = r;
    }
}

// ---------------- K6: output projection GEMM ----------------
__global__ __launch_bounds__(256) void out_gemm(
    const float* __restrict__ A, const float* __restrict__ W, float* __restrict__ out)
{
    const int rb = blockIdx.y*64, cb = blockIdx.x*64;
    __shared__ float As[16][68];
    __shared__ float Bs[16][68];
    const int tid = threadIdx.x;
    const int ty = tid>>4, tx = tid&15;
    const int ar = tid>>2, ac4 = (tid&3)<<2;
    const int bkr = tid>>4, bc4 = (tid&15)<<2;
    float acc[4][4] = {};
    for (int kb=0; kb<HDIM; kb+=16) {
        float4 av  = *(const float4*)&A[(size_t)(rb+ar)*HDIM + kb + ac4];
        float4 bvv = *(const float4*)&W[(size_t)(kb+bkr)*D_ + cb + bc4];
        __syncthreads();
        As[ac4+0][ar]=av.x; As[ac4+1][ar]=av.y; As[ac4+2][ar]=av.z; As[ac4+3][ar]=av.w;
        *(float4*)&Bs[bkr][bc4] = bvv;
        __syncthreads();
        #pragma unroll
        for (int kk=0; kk<16; kk++) {
            float a[4], b[4];
            *(float4*)a = *(const float4*)&As[kk][ty<<2];
            *(float4*)b = *(const float4*)&Bs[kk][tx<<2];
            #pragma unroll
            for (int i=0;i<4;i++)
                #pragma unroll
                for (int j=0;j<4;j++) acc[i][j] += a[i]*b[j];
        }
    }
    const int c0 = cb + (tx<<2);
    #pragma unroll
    for (int i=0;i<4;i++) {
        int n = rb + (ty<<2) + i;
        float4 r;
        r.x=acc[i][0]; r.y=acc[i][1]; r.z=acc[i][2]; r.w=acc[i][3];
        *(float4*)&out[(size_t)n*D_ + c0] = r;
    }
}

// ---------------- K2: RoPE in-place on q,k ----------------
__global__ __launch_bounds__(256) void rope_kernel(
    float* __restrict__ q, float* __restrict__ k,
    const float* __restrict__ cosb, const float* __restrict__ sinb)
{
    int t = blockIdx.x*256 + threadIdx.x;
    int pair = t & 31;
    int s    = (t>>5) & 511;
    int bh   = (t>>14) & 31;
    float* x = (t>>19) ? k : q;
    float* xb = x + ((size_t)(bh*S_ + s))*HD;
    float c  = cosb[s*HD + pair];
    float sn = sinb[s*HD + pair];
    float x1 = xb[pair], x2 = xb[pair+32];
    xb[pair]    = x1*c - x2*sn;
    xb[pair+32] = x2*c + x1*sn;
}

// ---------------- K3: MFMA sim + screen (dbuf, wave-skip ladder) -----------
// 256 blocks x 1024 thr (16 waves). Block: 64 queries x full M, tile=128,
// bf16 stream, double-buffered Ks+sc, ONE barrier/tile. Ladder guarded by
// __any(key > lane-min): skipping is exact (below-min inserts are no-ops on
// a sorted-desc list). Screen/rescore semantics identical to R21/R22.
__global__ __launch_bounds__(1024, 4) void sim_topk_mfma(
    const float* __restrict__ q, const float* __restrict__ memk,
    const unsigned short* __restrict__ kb16,
    float* __restrict__ topV, int* __restrict__ topI)
{
    __shared__ unsigned short sc[2][64][136];
    __shared__ __align__(16) float qs[64][64];
    __shared__ __align__(16) unsigned short Ks[2][128][76];
    const int tid = threadIdx.x;
    int id = blockIdx.x;                 // 0..255
    int virt = (id & 7)*32 + (id >> 3);
    const int bh = virt >> 3, qt = virt & 7;
    const float* qbase = q + ((size_t)bh*S_ + qt*64)*HD;
    const float* kbase = memk + (size_t)bh*M_*HD;
    const unsigned short* k16 = kb16 + (size_t)bh*M_*HD;

    {   // stage q f32 (64x64): one f32x4 per thread
        int r = tid >> 4, c = (tid & 15) << 2;
        *(f32x4*)&qs[r][c] = *(const f32x4*)&qbase[(size_t)r*HD + c];
    }
    __syncthreads();

    const int lane = tid & 63;
    const int w  = tid >> 6;                  // wave 0..15
    const int s8 = w & 7;                     // m-subtile (rows s8*16..+15)
    const int qg = w >> 3;                    // qh-group: qh = 2*qg, 2*qg+1
    const int fr = lane & 15, fc = lane >> 4; // frag row / k-chunk

    bf16x8 bq[2][2];
    #pragma unroll
    for (int j = 0; j < 2; j++)
        #pragma unroll
        for (int kc = 0; kc < 2; kc++) {
            const float* p = &qs[(2*qg + j)*16 + fr][kc*32 + 8*fc];
            union { bf16x8 v; unsigned u[4]; } u;
            #pragma unroll
            for (int jj = 0; jj < 4; jj++)
                u.u[jj] = pkbf(__float_as_uint(p[2*jj+1]), __float_as_uint(p[2*jj]));
            bq[j][kc] = u.v;
        }

    const int ql = tid >> 4, lg = tid & 15;   // query row / lane-in-group
    unsigned xs[LCAP];
    #pragma unroll
    for (int s = 0; s < LCAP; s++) xs[s] = 0u;

    const int srow = tid >> 3, scol = (tid & 7) << 3;

    uint4 pfu;
    {
        uint4 t0 = *(const uint4*)&k16[(size_t)srow*HD + scol];
        *(uint4*)&Ks[0][srow][scol] = t0;
        pfu = *(const uint4*)&k16[(size_t)(128 + srow)*HD + scol];
    }
    __syncthreads();   // Ks[0] ready

    for (int it = 0; it < 64; it++) {
        const int cur = it & 1, nxt = cur ^ 1;
        if (it < 63) {
            *(uint4*)&Ks[nxt][srow][scol] = pfu;
        }
        if (it < 62) {
            pfu = *(const uint4*)&k16[(size_t)((it+2)*128 + srow)*HD + scol];
        }
        {
            bf16x8 a0 = *(const bf16x8*)&Ks[cur][s8*16 + fr][8*fc];
            bf16x8 a1 = *(const bf16x8*)&Ks[cur][s8*16 + fr][32 + 8*fc];
            #pragma unroll
            for (int j = 0; j < 2; j++) {
                f32x4 acc = (f32x4){0.f, 0.f, 0.f, 0.f};
                acc = __builtin_amdgcn_mfma_f32_16x16x32_bf16(a0, bq[j][0], acc, 0,0,0);
                acc = __builtin_amdgcn_mfma_f32_16x16x32_bf16(a1, bq[j][1], acc, 0,0,0);
                unsigned k0 = key2(pkbf(__float_as_uint(acc.y), __float_as_uint(acc.x)));
                unsigned k1 = key2(pkbf(__float_as_uint(acc.w), __float_as_uint(acc.z)));
                uint2 kk; kk.x = k0; kk.y = k1;
                *(uint2*)&sc[cur][(2*qg + j)*16 + fr][s8*16 + 4*fc] = kk;
            }
        }
        if (it > 0) {
            uint4 w0v = *(const uint4*)&sc[cur^1][ql][lg << 3];
            unsigned wbuf[4] = {w0v.x, w0v.y, w0v.z, w0v.w};
            const unsigned ibase = (unsigned)((it-1)*128 + (lg << 3));
            #pragma unroll
            for (int p = 0; p < 4; p++) {
                unsigned wk = wbuf[p];
                unsigned ve = (wk << 16) | (ibase + 2*p);
                unsigned vo = (wk & 0xFFFF0000u) | (ibase + 2*p + 1);
                if (__any(ve > xs[LCAP-1] || vo > xs[LCAP-1])) {
                    #pragma unroll
                    for (int s = 0; s < LCAP; s++) {
                        unsigned mx = xs[s] > ve ? xs[s] : ve;
                        unsigned mn = xs[s] > ve ? ve : xs[s];
                        xs[s] = mx; ve = mn;
                    }
                    #pragma unroll
                    for (int s = 0; s < LCAP; s++) {
                        unsigned mx = xs[s] > vo ? xs[s] : vo;
                        unsigned mn = xs[s] > vo ? vo : xs[s];
                        xs[s] = mx; vo = mn;
                    }
                }
            }
        }
        __syncthreads();
    }
    {
        uint4 w0v = *(const uint4*)&sc[1][ql][lg << 3];
        unsigned wbuf[4] = {w0v.x, w0v.y, w0v.z, w0v.w};
        const unsigned ibase = (unsigned)(63*128 + (lg << 3));
        #pragma unroll
        for (int p = 0; p < 4; p++) {
            unsigned wk = wbuf[p];
            unsigned ve = (wk << 16) | (ibase + 2*p);
            unsigned vo = (wk & 0xFFFF0000u) | (ibase + 2*p + 1);
            if (__any(ve > xs[LCAP-1] || vo > xs[LCAP-1])) {
                #pragma unroll
                for (int s = 0; s < LCAP; s++) {
                    unsigned mx = xs[s] > ve ? xs[s] : ve;
                    unsigned mn = xs[s] > ve ? ve : xs[s];
                    xs[s] = mx; ve = mn;
                }
                #pragma unroll
                for (int s = 0; s < LCAP; s++) {
                    unsigned mx = xs[s] > vo ? xs[s] : vo;
                    unsigned mn = xs[s] > vo ? vo : xs[s];
                    xs[s] = mx; vo = mn;
                }
            }
        }
    }

    // ---- register extract: group top-48 by key -> 3 collector slots/lane --
    unsigned rc[NRES];
    #pragma unroll
    for (int it = 0; it < 48; it++) {
        unsigned gm = xs[0]; int go = lg;
        { unsigned ov=(unsigned)dppmov<0x140>((int)gm); int oo=dppmov<0x140>(go);
          if (ov > gm) { gm = ov; go = oo; } }
        { unsigned ov=(unsigned)dppmov<0x141>((int)gm); int oo=dppmov<0x141>(go);
          if (ov > gm) { gm = ov; go = oo; } }
        { unsigned ov=(unsigned)dppmov<0x4E>((int)gm);  int oo=dppmov<0x4E>(go);
          if (ov > gm) { gm = ov; go = oo; } }
        { unsigned ov=(unsigned)dppmov<0xB1>((int)gm);  int oo=dppmov<0xB1>(go);
          if (ov > gm) { gm = ov; go = oo; } }
        if (go == lg) {
            #pragma unroll
            for (int s = 0; s < LCAP-1; s++) xs[s] = xs[s+1];
            xs[LCAP-1] = 0u;
        }
        if ((it & 15) == lg) rc[it >> 4] = gm;
    }

    // ---- exact f32 rescore of my NRES candidates ----
    float rsv[NRES]; int rsi[NRES];
    #pragma unroll
    for (int s2 = 0; s2 < NRES; s2++) {
        int idx = (int)(rc[s2] & 0xFFFFu);
        const float* kr = &kbase[(size_t)idx * HD];
        float accr = 0.f;
        #pragma unroll
        for (int j = 0; j < 64; j += 4) {
            f32x4 kv = *(const f32x4*)&kr[j];
            f32x4 qv = *(const f32x4*)&qs[ql][j];
            accr += qv.x*kv.x + qv.y*kv.y + qv.z*kv.z + qv.w*kv.w;
        }
        rsv[s2] = accr; rsi[s2] = idx;
    }
    // ---- exact top-32 of 48 by extract-max (16-lane DPP argmax) ----
    const int qgb = bh*S_ + qt*64;
    float* tVo = &topV[(size_t)(qgb + ql)*32];
    int*   tIo = &topI[(size_t)(qgb + ql)*32];
    #pragma unroll 1
    for (int it = 0; it < 32; it++) {
        float mv = rsv[0]; int ms = 0;
        if (rsv[1] > mv) { mv = rsv[1]; ms = 1; }
        if (rsv[2] > mv) { mv = rsv[2]; ms = 2; }
        int owner = (lg << 2) | ms;
        { float ovf=__int_as_float(dppmov<0x140>(__float_as_int(mv))); int oo=dppmov<0x140>(owner);
          if (ovf>mv || (ovf==mv && oo<owner)) { mv=ovf; owner=oo; } }
        { float ovf=__int_as_float(dppmov<0x141>(__float_as_int(mv))); int oo=dppmov<0x141>(owner);
          if (ovf>mv || (ovf==mv && oo<owner)) { mv=ovf; owner=oo; } }
        { float ovf=__int_as_float(dppmov<0x4E>(__float_as_int(mv)));  int oo=dppmov<0x4E>(owner);
          if (ovf>mv || (ovf==mv && oo<owner)) { mv=ovf; owner=oo; } }
        { float ovf=__int_as_float(dppmov<0xB1>(__float_as_int(mv)));  int oo=dppmov<0xB1>(owner);
          if (ovf>mv || (ovf==mv && oo<owner)) { mv=ovf; owner=oo; } }
        if ((owner >> 2) == lg) {
            int ms2 = owner & 3;
            int idx = rsi[0];
            if (ms2 == 1) idx = rsi[1];
            else if (ms2 == 2) idx = rsi[2];
            if (ms2 == 0) rsv[0] = -INFINITY;
            else if (ms2 == 1) rsv[1] = -INFINITY;
            else rsv[2] = -INFINITY;
            tVo[it] = mv; tIo[it] = idx;
        }
    }
}

// ---------------- K5: fused local-causal + memory attention ----------------
__global__ __launch_bounds__(256) void attn_fused(
    const float* __restrict__ q, const float* __restrict__ k, const float* __restrict__ v,
    const float* __restrict__ topV, const int* __restrict__ topI,
    const float* __restrict__ memv, float* __restrict__ attn)
{
    __shared__ float Ks[64][68];
    __shared__ float Vs[64][68];
    __shared__ float Qs[32][68];
    __shared__ float pt[32][68];
    const int tid = threadIdx.x;
    const int qt = blockIdx.x, bh = blockIdx.y;
    const float* qbase = q + ((size_t)bh*S_ + qt*32)*HD;
    {
        int fi = tid; int r = fi>>4, c = (fi&15)<<2;
        float4 t4 = *(const float4*)&qbase[(size_t)r*HD + c];
        t4.x*=SCALE; t4.y*=SCALE; t4.z*=SCALE; t4.w*=SCALE;
        *(float4*)&Qs[r][c] = t4;
        fi = tid+256; r = fi>>4; c = (fi&15)<<2;
        t4 = *(const float4*)&qbase[(size_t)r*HD + c];
        t4.x*=SCALE; t4.y*=SCALE; t4.z*=SCALE; t4.w*=SCALE;
        *(float4*)&Qs[r][c] = t4;
    }
    __syncthreads();
    const int ql = tid>>3, lg = tid&7;
    const int dd0 = lg<<3;
    float qreg[64];
    #pragma unroll
    for (int j=0;j<64;j+=4) *(float4*)&qreg[j] = *(const float4*)&Qs[ql][j];
    const int qpos = qt*32 + ql;
    const size_t qg = (size_t)bh*S_ + qpos;

    float m = -INFINITY, l = 0.f;
    float acc[8] = {0,0,0,0,0,0,0,0};
    const float* tvp = &topV[qg*32];
    const int*   tip = &topI[qg*32];
    #pragma unroll 8
    for (int j=0;j<32;j++) m = fmaxf(m, tvp[j]*SCALE);
    #pragma unroll 4
    for (int j=0;j<32;j++) {
        float p = __expf(tvp[j]*SCALE - m);
        l += p;
        const float* mvr = &memv[((size_t)bh*M_ + tip[j])*HD + dd0];
        float4 a  = *(const float4*)&mvr[0];
        float4 b2 = *(const float4*)&mvr[4];
        acc[0]+=p*a.x;  acc[1]+=p*a.y;  acc[2]+=p*a.z;  acc[3]+=p*a.w;
        acc[4]+=p*b2.x; acc[5]+=p*b2.y; acc[6]+=p*b2.z; acc[7]+=p*b2.w;
    }
    const int ntiles = (qt*32 + 31)/64 + 1;
    const float* kb2 = k + ((size_t)bh*S_)*HD;
    const float* vb2 = v + ((size_t)bh*S_)*HD;
    for (int kt=0; kt<ntiles; kt++) {
        __syncthreads();
        for (int fi=tid; fi<1024; fi+=256) {
            int r = fi>>4, c = (fi&15)<<2;
            *(float4*)&Ks[r][c] = *(const float4*)&kb2[(size_t)(kt*64+r)*HD + c];
            *(float4*)&Vs[r][c] = *(const float4*)&vb2[(size_t)(kt*64+r)*HD + c];
        }
        __syncthreads();
        float s8[8];
        #pragma unroll
        for (int rr=0; rr<8; rr++) {
            int row = lg + (rr<<3);
            float acc2 = 0.f;
            #pragma unroll
            for (int j=0;j<64;j+=4) {
                float4 kv = *(const float4*)&Ks[row][j];
                acc2 += qreg[j]*kv.x + qreg[j+1]*kv.y + qreg[j+2]*kv.z + qreg[j+3]*kv.w;
            }
            int kpos = kt*64 + row;
            s8[rr] = (kpos <= qpos) ? acc2 : -INFINITY;
        }
        float tmax = s8[0];
        #pragma unroll
        for (int rr=1; rr<8; rr++) tmax = fmaxf(tmax, s8[rr]);
        #pragma unroll
        for (int off=1; off<8; off<<=1) tmax = fmaxf(tmax, __shfl_xor(tmax, off));
        float mnew = fmaxf(m, tmax);
        float f = __expf(m - mnew);
        l *= f;
        #pragma unroll
        for (int i=0;i<8;i++) acc[i] *= f;
        float psum = 0.f;
        #pragma unroll
        for (int rr=0; rr<8; rr++) {
            float p = __expf(s8[rr] - mnew);
            psum += p;
            pt[ql][lg + (rr<<3)] = p;
        }
        #pragma unroll
        for (int off=1; off<8; off<<=1) psum += __shfl_xor(psum, off);
        l += psum; m = mnew;
        #pragma unroll 8
        for (int r=0; r<64; r++) {
            float p = pt[ql][r];
            float4 a  = *(const float4*)&Vs[r][dd0];
            float4 b2 = *(const float4*)&Vs[r][dd0+4];
            acc[0]+=p*a.x;  acc[1]+=p*a.y;  acc[2]+=p*a.z;  acc[3]+=p*a.w;
            acc[4]+=p*b2.x; acc[5]+=p*b2.y; acc[6]+=p*b2.z; acc[7]+=p*b2.w;
        }
    }
    float inv = 1.0f / l;
    const int b = bh>>4, h = bh&15;
    float4 o;
    o.x=acc[0]*inv; o.y=acc[1]*inv; o.z=acc[2]*inv; o.w=acc[3]*inv;
    *(float4*)&attn[((size_t)(b*S_)+qpos)*HDIM + h*HD + dd0] = o;
    o.x=acc[4]*inv; o.y=acc[5]*inv; o.z=acc[6]*inv; o.w=acc[7]*inv;
    *(float4*)&attn[((size_t)(b*S_)+qpos)*HDIM + h*HD + dd0 + 4] = o;
}

extern "C" void kernel_launch(void* const* d_in, const int* in_sizes, int n_in,
                              void* d_out, int out_size, void* d_ws, size_t ws_size,
                              hipStream_t stream)
{
    const float* hs   = (const float*)d_in[0];
    const float* cosb = (const float*)d_in[1];
    const float* sinb = (const float*)d_in[2];
    const float* memk = (const float*)d_in[3];
    const float* memv = (const float*)d_in[4];
    const float* Wq = (const float*)d_in[5];
    const float* bq = (const float*)d_in[6];
    const float* Wk = (const float*)d_in[7];
    const float* bk = (const float*)d_in[8];
    const float* Wv = (const float*)d_in[9];
    const float* bv = (const float*)d_in[10];
    const float* Wo = (const float*)d_in[11];
    float* out = (float*)d_out;
    float* ws = (float*)d_ws;
    float* qw = ws;                    // 1M floats
    float* kw = ws + 1048576;          // 1M
    float* vw = ws + 2097152;          // 1M
    float* tV = ws + 3145728;          // 512K
    int*   tI = (int*)(ws + 3670016);  // 512K
    unsigned short* kb16 = (unsigned short*)(ws + 4194304); // 8.39M float-slots
    float* ao = ws + 4194304;          // aliases kb16 (dead before attn writes)

    tobf16<<<8192,256,0,stream>>>(memk, kb16);
    qkv_gemm<<<dim3(16,16,3),256,0,stream>>>(hs, Wq,bq,Wk,bk,Wv,bv, qw,kw,vw);
    rope_kernel<<<4096,256,0,stream>>>(qw,kw,cosb,sinb);
    sim_topk_mfma<<<256,1024,0,stream>>>(qw, memk, kb16, tV, tI);
    attn_fused<<<dim3(16,32),256,0,stream>>>(qw,kw,vw, tV,tI, memv, ao);
    out_gemm<<<dim3(16,16),256,0,stream>>>(ao, Wo, out);
}